// Round 14
// baseline (548.635 us; speedup 1.0000x reference)
//
#include <hip/hip_runtime.h>

typedef _Float16 f16;
typedef _Float16 f16x8 __attribute__((ext_vector_type(8)));
typedef float f32x4 __attribute__((ext_vector_type(4)));

#define LDS_GL16(g, l) __builtin_amdgcn_global_load_lds( \
    (const __attribute__((address_space(1))) void*)(g),  \
    (__attribute__((address_space(3))) void*)(l), 16, 0, 0)
#define VMCNT(N) asm volatile("s_waitcnt vmcnt(" #N ")" ::: "memory")
#define BAR() __builtin_amdgcn_s_barrier()

// ---- fused prep: f32->f16 converts (qw/kvw/hid) + RMSNorm -----------------
__global__ __launch_bounds__(256) void prep_kern(
        const float* __restrict__ qw,   f16* __restrict__ qwh,
        const float* __restrict__ kvw,  f16* __restrict__ kvwh,
        const float* __restrict__ hid,  f16* __restrict__ hidh,
        const float* __restrict__ x, const float* __restrict__ lnsc,
        f16* __restrict__ xnh) {
    int b = blockIdx.x;
    if (b >= 14336) {   // RMSNorm row
        long base = (long)(b - 14336) * 2048 + threadIdx.x * 8;
        float4 a = *(const float4*)(x + base);
        float4 v = *(const float4*)(x + base + 4);
        float ss = a.x*a.x + a.y*a.y + a.z*a.z + a.w*a.w
                 + v.x*v.x + v.y*v.y + v.z*v.z + v.w*v.w;
        #pragma unroll
        for (int d = 1; d < 64; d <<= 1) ss += __shfl_xor(ss, d, 64);
        __shared__ float red[4];
        if ((threadIdx.x & 63) == 0) red[threadIdx.x >> 6] = ss;
        __syncthreads();
        ss = red[0] + red[1] + red[2] + red[3];
        float inv = 1.0f / (sqrtf(ss * (1.0f / 2048.0f)) + 1e-8f);
        int c = threadIdx.x * 8;
        float4 s1 = *(const float4*)(lnsc + c);
        float4 s2 = *(const float4*)(lnsc + c + 4);
        f16x8 o = { (f16)(a.x*inv*s1.x),(f16)(a.y*inv*s1.y),(f16)(a.z*inv*s1.z),(f16)(a.w*inv*s1.w),
                    (f16)(v.x*inv*s2.x),(f16)(v.y*inv*s2.y),(f16)(v.z*inv*s2.z),(f16)(v.w*inv*s2.w) };
        *(f16x8*)(xnh + base) = o;
        return;
    }
    const float* in; f16* out; long base;
    if (b < 2048)       { in = qw;   out = qwh;   base = (long)b * 2048; }
    else if (b < 6144)  { in = kvw;  out = kvwh;  base = (long)(b - 2048) * 2048; }
    else                { in = hid;  out = hidh;  base = (long)(b - 6144) * 2048; }
    long o = base + threadIdx.x * 8;
    float4 a = *(const float4*)(in + o);
    float4 c = *(const float4*)(in + o + 4);
    f16x8 v = { (f16)a.x,(f16)a.y,(f16)a.z,(f16)a.w,
                (f16)c.x,(f16)c.y,(f16)c.z,(f16)c.w };
    *(f16x8*)(out + o) = v;
}

// ---------------- GEMM 256x256 body, BK=64, 8 waves, 8-phase pipelined -----
// C[M,N] = A[M,K] * B[N,K]^T.  EPI=0: f16 out. EPI=1: f32 out + resid.
// Stage/vmcnt/barrier schedule identical to R9 (proven ledger).  NEW: frags
// prefetched ONE PHASE EARLY into double-buffered regs (a0/a1, b0e/b0o, b1);
// each phase = {stage; [vmcnt]; BAR; prefetch(p+1); mma(p); BAR} so the LDS
// read service overlaps the MFMA burst instead of serializing with it.
template<int EPI>
__device__ __forceinline__ void gemm256_body(
        const f16* __restrict__ A, const f16* __restrict__ B,
        f16* __restrict__ Ch, float* __restrict__ Cf,
        const float* __restrict__ resid, int N, int Kd, int m0, int n0) {
    alignas(16) __shared__ f16 lds[65536];
    int tid = threadIdx.x, lane = tid & 63;
    int wid = tid >> 6, wm = wid >> 2, wn = wid & 3;
    int lr = lane & 15, g = lane >> 4;
    int iL = tid >> 3, cb = tid & 7;

    long goff[8]; int doff[8];
    #pragma unroll
    for (int rd = 0; rd < 2; ++rd) {
        int rA0 = iL + rd * 128;
        goff[0 + rd] = (long)(m0 + rA0) * Kd + ((cb ^ (rA0 & 7)) << 3);
        doff[0 + rd] = rA0 * 64 + cb * 8;
        int rB0 = (iL & 31) + ((iL >> 5) + rd * 2) * 64;
        goff[2 + rd] = (long)(n0 + rB0) * Kd + ((cb ^ (rB0 & 7)) << 3);
        doff[2 + rd] = 32768 + rB0 * 64 + cb * 8;
        int rB1 = rB0 + 32;
        goff[4 + rd] = (long)(n0 + rB1) * Kd + ((cb ^ (rB1 & 7)) << 3);
        doff[4 + rd] = 32768 + rB1 * 64 + cb * 8;
        int rA1 = rA0 + 64;
        goff[6 + rd] = (long)(m0 + rA1) * Kd + ((cb ^ (rA1 & 7)) << 3);
        doff[6 + rd] = rA1 * 64 + cb * 8;
    }
    auto stage = [&](int kt, int p, int r) {
        const f16* src = (r == 0 || r == 3) ? A : B;
        #pragma unroll
        for (int rd = 0; rd < 2; ++rd)
            LDS_GL16(src + goff[r * 2 + rd] + kt * 64,
                     lds + p * 16384 + doff[r * 2 + rd]);
    };

    const char* ldsc = (const char*)lds;
    int swz = lr & 7;
    const char* baseA[2], *baseB[2];
    baseA[0] = ldsc + (wm * 128 + lr) * 128 + ((g ^ swz) << 4);
    baseA[1] = ldsc + (wm * 128 + lr) * 128 + (((4 + g) ^ swz) << 4);
    baseB[0] = ldsc + 65536 + (wn * 64 + lr) * 128 + ((g ^ swz) << 4);
    baseB[1] = ldsc + 65536 + (wn * 64 + lr) * 128 + (((4 + g) ^ swz) << 4);

    f32x4 acc[8][4] = {};
    f16x8 a0[4][2], a1[4][2], b0e[2][2], b0o[2][2], b1[2][2];

    auto loadA = [&](f16x8 (&d)[4][2], int bufB, int qm) {
        #pragma unroll
        for (int mf = 0; mf < 4; ++mf)
            #pragma unroll
            for (int kk = 0; kk < 2; ++kk)
                d[mf][kk] = *(const f16x8*)(baseA[kk] + bufB + qm * 8192 + mf * 2048);
    };
    auto loadB = [&](f16x8 (&d)[2][2], int bufB, int qn) {
        #pragma unroll
        for (int nf = 0; nf < 2; ++nf)
            #pragma unroll
            for (int kk = 0; kk < 2; ++kk)
                d[nf][kk] = *(const f16x8*)(baseB[kk] + bufB + qn * 4096 + nf * 2048);
    };
    auto mma = [&](f16x8 (&aa)[4][2], f16x8 (&bb)[2][2], int qm, int qn) {
        __builtin_amdgcn_s_setprio(1);
        #pragma unroll
        for (int kk = 0; kk < 2; ++kk)
            #pragma unroll
            for (int mf = 0; mf < 4; ++mf)
                #pragma unroll
                for (int nf = 0; nf < 2; ++nf)
                    acc[qm * 4 + mf][qn * 2 + nf] = __builtin_amdgcn_mfma_f32_16x16x32_f16(
                        aa[mf][kk], bb[nf][kk], acc[qm * 4 + mf][qn * 2 + nf], 0, 0, 0);
        __builtin_amdgcn_s_setprio(0);
    };

    int NT = Kd >> 6, NI = NT >> 1;

    stage(0, 0, 0); stage(0, 0, 1); stage(0, 0, 2); stage(0, 0, 3);
    stage(1, 1, 0); stage(1, 1, 1); stage(1, 1, 2);
    VMCNT(6); BAR();                 // tile0 landed; 6 in flight
    loadA(a0, 0, 0); loadB(b0e, 0, 0);   // frags for p1/p2

    for (int it = 0; it < NI - 1; ++it) {
        int t0 = it * 2;
        // p1: prefetch b1 (p2); mma q(0,0) tile t0
        stage(t0 + 1, 1, 3);
        BAR(); loadB(b1, 0, 1);  mma(a0, b0e, 0, 0); BAR();
        // p2: prefetch a1 (p3)
        stage(t0 + 2, 0, 0);
        BAR(); loadA(a1, 0, 1);  mma(a0, b1, 0, 1); BAR();
        // p3: no prefetch (p4 uses held a1,b0e)
        stage(t0 + 2, 0, 1);
        BAR();                   mma(a1, b1, 1, 1); BAR();
        // p4: tile t0+1 landed; prefetch a0,b0o from buf1 (p5)
        stage(t0 + 2, 0, 2);
        VMCNT(6);
        BAR(); loadA(a0, 32768, 0); loadB(b0o, 32768, 0);  mma(a1, b0e, 1, 0); BAR();
        // p5: prefetch b1 (p6); mma q(0,0) tile t0+1
        stage(t0 + 2, 0, 3);
        BAR(); loadB(b1, 32768, 1);  mma(a0, b0o, 0, 0); BAR();
        // p6: prefetch a1 (p7)
        stage(t0 + 3, 1, 0);
        BAR(); loadA(a1, 32768, 1);  mma(a0, b1, 0, 1); BAR();
        // p7
        stage(t0 + 3, 1, 1);
        BAR();                   mma(a1, b1, 1, 1); BAR();
        // p8: tile t0+2 landed; prefetch a0,b0e from buf0 (next p1)
        stage(t0 + 3, 1, 2);
        VMCNT(6);
        BAR(); loadA(a0, 0, 0); loadB(b0e, 0, 0);  mma(a1, b0o, 1, 0); BAR();
    }
    {   // final iteration (tiles NT-2, NT-1)
        stage(NT - 1, 1, 3);
        BAR(); loadB(b1, 0, 1);  mma(a0, b0e, 0, 0); BAR();
        BAR(); loadA(a1, 0, 1);  mma(a0, b1, 0, 1); BAR();
        BAR();                   mma(a1, b1, 1, 1); BAR();
        VMCNT(0);                // tile NT-1 fully landed
        BAR(); loadA(a0, 32768, 0); loadB(b0o, 32768, 0);  mma(a1, b0e, 1, 0); BAR();
        BAR(); loadB(b1, 32768, 1);  mma(a0, b0o, 0, 0); BAR();
        BAR(); loadA(a1, 32768, 1);  mma(a0, b1, 0, 1); BAR();
        BAR();                   mma(a1, b1, 1, 1); BAR();
        mma(a1, b0o, 1, 0);
    }

    // ---- epilogue: LDS bounce (XOR de-conflict) -> coalesced stores ----
    __syncthreads();
    if (EPI == 0) {
        #pragma unroll
        for (int i = 0; i < 8; ++i)
            #pragma unroll
            for (int j = 0; j < 4; ++j)
                #pragma unroll
                for (int reg = 0; reg < 4; ++reg) {
                    int row = wm * 128 + i * 16 + g * 4 + reg;
                    int col = (wn * 64 + j * 16 + lr) ^ ((row & 12) << 2);
                    lds[row * 256 + col] = (f16)acc[i][j][reg];
                }
        __syncthreads();
        #pragma unroll
        for (int k = 0; k < 16; ++k) {
            int e = k * 4096 + tid * 8;          // f16 elem in [256][256]
            int row = e >> 8, col = e & 255;
            *(f16x8*)(Ch + (long)(m0 + row) * N + n0 + col) =
                *(const f16x8*)(lds + row * 256 + (col ^ ((row & 12) << 2)));
        }
    } else {
        float* Ct = (float*)lds;                 // [128][256] f32 per pass
        #pragma unroll
        for (int h = 0; h < 2; ++h) {
            if (h) __syncthreads();
            if (wm == h) {
                #pragma unroll
                for (int i = 0; i < 8; ++i)
                    #pragma unroll
                    for (int j = 0; j < 4; ++j)
                        #pragma unroll
                        for (int reg = 0; reg < 4; ++reg) {
                            int row = i * 16 + g * 4 + reg;
                            int col = (wn * 64 + j * 16 + lr) ^ ((row & 4) << 2);
                            Ct[row * 256 + col] = acc[i][j][reg];
                        }
            }
            float4 ra[8], rb[8];
            #pragma unroll
            for (int k = 0; k < 8; ++k) {
                int e = k * 4096 + tid * 8;
                int row = e >> 8, col = e & 255;
                long gi = (long)(m0 + h * 128 + row) * N + n0 + col;
                ra[k] = *(const float4*)(resid + gi);
                rb[k] = *(const float4*)(resid + gi + 4);
            }
            __syncthreads();
            #pragma unroll
            for (int k = 0; k < 8; ++k) {
                int e = k * 4096 + tid * 8;      // f32 elem in [128][256]
                int row = e >> 8, col = e & 255;
                int pc = col ^ ((row & 4) << 2);
                long gi = (long)(m0 + h * 128 + row) * N + n0 + col;
                float4 c0 = *(const float4*)(Ct + row * 256 + pc);
                float4 c1 = *(const float4*)(Ct + row * 256 + pc + 4);
                c0.x += ra[k].x; c0.y += ra[k].y; c0.z += ra[k].z; c0.w += ra[k].w;
                c1.x += rb[k].x; c1.y += rb[k].y; c1.z += rb[k].z; c1.w += rb[k].w;
                *(float4*)(Cf + gi) = c0;
                *(float4*)(Cf + gi + 4) = c1;
            }
        }
    }
}

// ---- merged q+kv projection: grid 768 (q: 256 blocks, kv: 512 blocks) -----
__global__ __launch_bounds__(512, 2) void gemm_qkv(
        const f16* __restrict__ Aq, const f16* __restrict__ Bq, f16* __restrict__ Cq,
        const f16* __restrict__ Akv, const f16* __restrict__ Bkv, f16* __restrict__ Ckv) {
    int fid = (blockIdx.x & 7) * 96 + (blockIdx.x >> 3);   // XCD swizzle, 768 = 8*96
    const f16 *A, *B; f16* C; int N, lf, sh;
    if (fid < 256) { A = Aq;  B = Bq;  C = Cq;  N = 2048; lf = fid;       sh = 3; }
    else           { A = Akv; B = Bkv; C = Ckv; N = 4096; lf = fid - 256; sh = 4; }
    int by = lf >> sh, bx = lf & ((1 << sh) - 1);
    gemm256_body<0>(A, B, C, nullptr, nullptr, N, 2048, by << 8, bx << 8);
}

// ---- output projection + residual: grid 256 ----
__global__ __launch_bounds__(512, 2) void gemm_out(
        const f16* __restrict__ A, const f16* __restrict__ B,
        float* __restrict__ Cf, const float* __restrict__ resid) {
    int fid = (blockIdx.x & 7) * 32 + (blockIdx.x >> 3);   // 256 = 8*32
    int by = fid >> 3, bx = fid & 7;
    gemm256_body<1>(A, B, nullptr, Cf, resid, 2048, 2048, by << 8, bx << 8);
}

// ---------------- Attention + outw convert: grid 4096 ----------------------
__global__ __launch_bounds__(256, 2) void attn_kern(
        const f16* __restrict__ Q,    // [8192, 2048]
        const f16* __restrict__ KV,   // [8192, 4096]  (k | v)
        const float* __restrict__ mask,      // [64*128]
        const float* __restrict__ bias,      // [32*16]
        float* __restrict__ attn_out,        // (B,L,K,H,R,M) f32
        f16* __restrict__ pv_out,            // [8192, 2048]
        const float* __restrict__ outw, f16* __restrict__ outwh) {
    if (blockIdx.x >= 2048) {   // outw conversion
        long o = (long)(blockIdx.x - 2048) * 2048 + threadIdx.x * 8;
        float4 a = *(const float4*)(outw + o);
        float4 c = *(const float4*)(outw + o + 4);
        f16x8 v = { (f16)a.x,(f16)a.y,(f16)a.z,(f16)a.w,
                    (f16)c.x,(f16)c.y,(f16)c.z,(f16)c.w };
        *(f16x8*)(outwh + o) = v;
        return;
    }
    __shared__ f16 Vt[128 * 128];
    __shared__ f16 P[64 * 136];
    int blk = blockIdx.x;
    int h  = blk & 15;
    int bk = blk >> 4;
    int bl = bk >> 1;
    int tid = threadIdx.x, lane = tid & 63, w = tid >> 6;
    int r0 = w << 4;
    int lr = lane & 15, g = lane >> 4;
    long qbase  = (long)bk * 64 * 2048;
    long kvbase = (long)bl * 128 * 4096;
    f16x8 vreg[8];
    const f16* vsrc = KV + kvbase + 2048 + h * 128;
    #pragma unroll
    for (int rnd = 0; rnd < 8; ++rnd) {
        int idx = tid + rnd * 256;
        vreg[rnd] = *(const f16x8*)(vsrc + (long)(idx >> 4) * 4096 + (idx & 15) * 8);
    }
    f16x8 aq[4];
    const f16* qrow = Q + qbase + (long)(r0 + lr) * 2048 + h * 128 + g * 8;
    #pragma unroll
    for (int t4 = 0; t4 < 4; ++t4) aq[t4] = *(const f16x8*)(qrow + t4 * 32);
    f32x4 s[8] = {};
    const f16* kbase = KV + kvbase + h * 128 + g * 8;
    #pragma unroll
    for (int j = 0; j < 8; ++j) {
        #pragma unroll
        for (int t4 = 0; t4 < 4; ++t4) {
            f16x8 bkf = *(const f16x8*)(kbase + (long)(j * 16 + lr) * 4096 + t4 * 32);
            s[j] = __builtin_amdgcn_mfma_f32_16x16x32_f16(aq[t4], bkf, s[j], 0, 0, 0);
        }
    }
    float madd[8];
    #pragma unroll
    for (int j = 0; j < 8; ++j)
        madd[j] = (1.0f - mask[(long)bl * 128 + j * 16 + lr]) * -10000.0f;
    #pragma unroll
    for (int reg = 0; reg < 4; ++reg) {
        int r = r0 + g * 4 + reg;
        float mx = -3.0e38f;
        #pragma unroll
        for (int j = 0; j < 8; ++j) {
            int m = j * 16 + lr;
            int rel = m - r;
            int bkt = (rel < -15 ? -15 : (rel > 16 ? 16 : rel)) + 15;
            float v = s[j][reg] + bias[bkt * 16 + h] + madd[j];
            s[j][reg] = v;
            mx = fmaxf(mx, v);
        }
        #pragma unroll
        for (int d = 1; d < 16; d <<= 1) mx = fmaxf(mx, __shfl_xor(mx, d, 64));
        float sum = 0.0f;
        #pragma unroll
        for (int j = 0; j < 8; ++j) {
            float e = __expf(s[j][reg] - mx);
            s[j][reg] = e;
            sum += e;
        }
        #pragma unroll
        for (int d = 1; d < 16; d <<= 1) sum += __shfl_xor(sum, d, 64);
        float inv = 1.0f / sum;
        #pragma unroll
        for (int j = 0; j < 8; ++j) s[j][reg] *= inv;
    }
    long abase = (long)blk * 64 * 128;
    #pragma unroll
    for (int reg = 0; reg < 4; ++reg) {
        int r = r0 + g * 4 + reg;
        #pragma unroll
        for (int j = 0; j < 8; ++j) {
            attn_out[abase + (long)r * 128 + j * 16 + lr] = s[j][reg];
            P[r * 136 + j * 16 + lr] = (f16)s[j][reg];
        }
    }
    {
        char* vtb = (char*)Vt;
        #pragma unroll
        for (int rnd = 0; rnd < 8; ++rnd) {
            int idx = tid + rnd * 256;
            int k = idx >> 4, c0 = (idx & 15) * 8;
            #pragma unroll
            for (int i = 0; i < 8; ++i) {
                int c = c0 + i;
                int sx = ((c >> 3) ^ i) & 7;
                *(f16*)(vtb + c * 256 + ((k * 2) ^ (sx << 4))) = vreg[rnd][i];
            }
        }
    }
    __syncthreads();
    f16x8 pa[4];
    #pragma unroll
    for (int t4 = 0; t4 < 4; ++t4)
        pa[t4] = *(const f16x8*)(P + (r0 + lr) * 136 + t4 * 32 + g * 8);
    f32x4 o[8] = {};
    const char* vtb = (const char*)Vt;
    #pragma unroll
    for (int dj = 0; dj < 8; ++dj) {
        int c = dj * 16 + lr;
        int sc = (((c >> 3) ^ (c & 7)) & 7) << 4;
        const char* vrow = vtb + c * 256;
        #pragma unroll
        for (int t4 = 0; t4 < 4; ++t4) {
            f16x8 bv = *(const f16x8*)(vrow + ((t4 * 64 + g * 16) ^ sc));
            o[dj] = __builtin_amdgcn_mfma_f32_16x16x32_f16(pa[t4], bv, o[dj], 0, 0, 0);
        }
    }
    __syncthreads();
    #pragma unroll
    for (int dj = 0; dj < 8; ++dj)
        #pragma unroll
        for (int reg = 0; reg < 4; ++reg) {
            int row = r0 + g * 4 + reg;
            int col = (dj * 16 + lr) ^ ((row & 12) << 2);
            Vt[row * 128 + col] = (f16)o[dj][reg];
        }
    __syncthreads();
    f16* ob = pv_out + qbase + h * 128;
    #pragma unroll
    for (int k = 0; k < 4; ++k) {
        int e = k * 2048 + tid * 8;
        int row = e >> 7, col = e & 127;
        *(f16x8*)(ob + (long)row * 2048 + col) =
            *(const f16x8*)(Vt + row * 128 + (col ^ ((row & 12) << 2)));
    }
}

extern "C" void kernel_launch(void* const* d_in, const int* in_sizes, int n_in,
                              void* d_out, int out_size, void* d_ws, size_t ws_size,
                              hipStream_t stream) {
    const float* x     = (const float*)d_in[0];
    const float* hid   = (const float*)d_in[1];
    const float* mask  = (const float*)d_in[2];
    const float* lnsc  = (const float*)d_in[3];
    const float* q_w   = (const float*)d_in[4];
    const float* kv_w  = (const float*)d_in[5];
    const float* out_w = (const float*)d_in[6];
    const float* bias  = (const float*)d_in[7];
    float* out0 = (float*)d_out;             // (B,L,K,R,Dm) = 16,777,216 f32
    float* attn = out0 + 16777216;           // (B,L,K,H,R,M) = 16,777,216 f32

    f16* kv_h  = (f16*)out0;                 // dead until final GEMM
    f16* xn_h  = (f16*)attn;                 // dead until attn_kern writes attn
    f16* hid_h = (f16*)(attn + 8388608);
    char* ws = (char*)d_ws;
    f16* q_h    = (f16*)(ws);                 // 32 MiB
    f16* ao_h   = (f16*)(ws + 33554432L);     // 32 MiB
    f16* qw_h   = (f16*)(ws + 67108864L);     //  8 MiB
    f16* kvw_h  = (f16*)(ws + 75497472L);     // 16 MiB
    f16* outw_h = (f16*)(ws + 92274688L);     //  8 MiB -> 96 MiB total

    prep_kern<<<22528, 256, 0, stream>>>(q_w, qw_h, kv_w, kvw_h,
                                         hid, hid_h, x, lnsc, xn_h);
    gemm_qkv<<<768, 512, 0, stream>>>(xn_h, qw_h, q_h, hid_h, kvw_h, kv_h);
    attn_kern<<<4096, 256, 0, stream>>>(q_h, kv_h, mask, bias, attn, ao_h,
                                        out_w, outw_h);
    gemm_out<<<256, 512, 0, stream>>>(ao_h, outw_h, out0, x);
}

// Round 15
// 370.788 us; speedup vs baseline: 1.4796x; 1.4796x over previous
//
#include <hip/hip_runtime.h>

typedef _Float16 f16;
typedef _Float16 f16x8 __attribute__((ext_vector_type(8)));
typedef float f32x4 __attribute__((ext_vector_type(4)));

#define LDS_GL16(g, l) __builtin_amdgcn_global_load_lds( \
    (const __attribute__((address_space(1))) void*)(g),  \
    (__attribute__((address_space(3))) void*)(l), 16, 0, 0)
#define VMCNT(N) asm volatile("s_waitcnt vmcnt(" #N ")" ::: "memory")
#define BAR() __builtin_amdgcn_s_barrier()

// ---- fused prep: f32->f16 converts (qw/kvw/hid) + RMSNorm -----------------
__global__ __launch_bounds__(256) void prep_kern(
        const float* __restrict__ qw,   f16* __restrict__ qwh,
        const float* __restrict__ kvw,  f16* __restrict__ kvwh,
        const float* __restrict__ hid,  f16* __restrict__ hidh,
        const float* __restrict__ x, const float* __restrict__ lnsc,
        f16* __restrict__ xnh) {
    int b = blockIdx.x;
    if (b >= 14336) {   // RMSNorm row
        long base = (long)(b - 14336) * 2048 + threadIdx.x * 8;
        float4 a = *(const float4*)(x + base);
        float4 v = *(const float4*)(x + base + 4);
        float ss = a.x*a.x + a.y*a.y + a.z*a.z + a.w*a.w
                 + v.x*v.x + v.y*v.y + v.z*v.z + v.w*v.w;
        #pragma unroll
        for (int d = 1; d < 64; d <<= 1) ss += __shfl_xor(ss, d, 64);
        __shared__ float red[4];
        if ((threadIdx.x & 63) == 0) red[threadIdx.x >> 6] = ss;
        __syncthreads();
        ss = red[0] + red[1] + red[2] + red[3];
        float inv = 1.0f / (sqrtf(ss * (1.0f / 2048.0f)) + 1e-8f);
        int c = threadIdx.x * 8;
        float4 s1 = *(const float4*)(lnsc + c);
        float4 s2 = *(const float4*)(lnsc + c + 4);
        f16x8 o = { (f16)(a.x*inv*s1.x),(f16)(a.y*inv*s1.y),(f16)(a.z*inv*s1.z),(f16)(a.w*inv*s1.w),
                    (f16)(v.x*inv*s2.x),(f16)(v.y*inv*s2.y),(f16)(v.z*inv*s2.z),(f16)(v.w*inv*s2.w) };
        *(f16x8*)(xnh + base) = o;
        return;
    }
    const float* in; f16* out; long base;
    if (b < 2048)       { in = qw;   out = qwh;   base = (long)b * 2048; }
    else if (b < 6144)  { in = kvw;  out = kvwh;  base = (long)(b - 2048) * 2048; }
    else                { in = hid;  out = hidh;  base = (long)(b - 6144) * 2048; }
    long o = base + threadIdx.x * 8;
    float4 a = *(const float4*)(in + o);
    float4 c = *(const float4*)(in + o + 4);
    f16x8 v = { (f16)a.x,(f16)a.y,(f16)a.z,(f16)a.w,
                (f16)c.x,(f16)c.y,(f16)c.z,(f16)c.w };
    *(f16x8*)(out + o) = v;
}

// ---------------- GEMM 256x256 body, BK=64, 8 waves, 8-phase pipelined -----
// C[M,N] = A[M,K] * B[N,K]^T.  EPI=0: f16 out. EPI=1: f32 out + resid.
// R9/R13-proven schedule (vmcnt(6) at p4/p8 only; b0 preloaded post-mma).
// Micro-opt: b1 loads moved one phase early (p1/p5) -> p2/p6 mma has no
// same-phase ds_reads.  Zero extra registers; WAR-safe (prior b1 value last
// consumed 2 barriers earlier; regions landed per ledger).
template<int EPI>
__device__ __forceinline__ void gemm256_body(
        const f16* __restrict__ A, const f16* __restrict__ B,
        f16* __restrict__ Ch, float* __restrict__ Cf,
        const float* __restrict__ resid, int N, int Kd, int m0, int n0) {
    alignas(16) __shared__ f16 lds[65536];
    int tid = threadIdx.x, lane = tid & 63;
    int wid = tid >> 6, wm = wid >> 2, wn = wid & 3;
    int lr = lane & 15, g = lane >> 4;
    int iL = tid >> 3, cb = tid & 7;

    long goff[8]; int doff[8];
    #pragma unroll
    for (int rd = 0; rd < 2; ++rd) {
        int rA0 = iL + rd * 128;
        goff[0 + rd] = (long)(m0 + rA0) * Kd + ((cb ^ (rA0 & 7)) << 3);
        doff[0 + rd] = rA0 * 64 + cb * 8;
        int rB0 = (iL & 31) + ((iL >> 5) + rd * 2) * 64;
        goff[2 + rd] = (long)(n0 + rB0) * Kd + ((cb ^ (rB0 & 7)) << 3);
        doff[2 + rd] = 32768 + rB0 * 64 + cb * 8;
        int rB1 = rB0 + 32;
        goff[4 + rd] = (long)(n0 + rB1) * Kd + ((cb ^ (rB1 & 7)) << 3);
        doff[4 + rd] = 32768 + rB1 * 64 + cb * 8;
        int rA1 = rA0 + 64;
        goff[6 + rd] = (long)(m0 + rA1) * Kd + ((cb ^ (rA1 & 7)) << 3);
        doff[6 + rd] = rA1 * 64 + cb * 8;
    }
    auto stage = [&](int kt, int p, int r) {
        const f16* src = (r == 0 || r == 3) ? A : B;
        #pragma unroll
        for (int rd = 0; rd < 2; ++rd)
            LDS_GL16(src + goff[r * 2 + rd] + kt * 64,
                     lds + p * 16384 + doff[r * 2 + rd]);
    };

    const char* ldsc = (const char*)lds;
    int swz = lr & 7;
    const char* baseA[2], *baseB[2];
    baseA[0] = ldsc + (wm * 128 + lr) * 128 + ((g ^ swz) << 4);
    baseA[1] = ldsc + (wm * 128 + lr) * 128 + (((4 + g) ^ swz) << 4);
    baseB[0] = ldsc + 65536 + (wn * 64 + lr) * 128 + ((g ^ swz) << 4);
    baseB[1] = ldsc + 65536 + (wn * 64 + lr) * 128 + (((4 + g) ^ swz) << 4);

    f32x4 acc[8][4] = {};
    f16x8 a[4][2], b0[2][2], b1[2][2];

    auto loadA = [&](int bufB, int qm) {
        #pragma unroll
        for (int mf = 0; mf < 4; ++mf)
            #pragma unroll
            for (int kk = 0; kk < 2; ++kk)
                a[mf][kk] = *(const f16x8*)(baseA[kk] + bufB + qm * 8192 + mf * 2048);
    };
    auto loadB = [&](f16x8 (&d)[2][2], int bufB, int qn) {
        #pragma unroll
        for (int nf = 0; nf < 2; ++nf)
            #pragma unroll
            for (int kk = 0; kk < 2; ++kk)
                d[nf][kk] = *(const f16x8*)(baseB[kk] + bufB + qn * 4096 + nf * 2048);
    };
    auto mma = [&](f16x8 (&bb)[2][2], int qm, int qn) {
        __builtin_amdgcn_s_setprio(1);
        #pragma unroll
        for (int kk = 0; kk < 2; ++kk)
            #pragma unroll
            for (int mf = 0; mf < 4; ++mf)
                #pragma unroll
                for (int nf = 0; nf < 2; ++nf)
                    acc[qm * 4 + mf][qn * 2 + nf] = __builtin_amdgcn_mfma_f32_16x16x32_f16(
                        a[mf][kk], bb[nf][kk], acc[qm * 4 + mf][qn * 2 + nf], 0, 0, 0);
        __builtin_amdgcn_s_setprio(0);
    };

    int NT = Kd >> 6, NI = NT >> 1;

    stage(0, 0, 0); stage(0, 0, 1); stage(0, 0, 2); stage(0, 0, 3);
    stage(1, 1, 0); stage(1, 1, 1); stage(1, 1, 2);
    VMCNT(6); BAR();                 // tile0 landed; 6 in flight
    loadB(b0, 0, 0);                 // preload b0 for first p1

    for (int it = 0; it < NI - 1; ++it) {
        int t0 = it * 2;
        // p1 (b1 prefetched here for p2)
        loadA(0, 0); loadB(b1, 0, 1);
        stage(t0 + 1, 1, 3);
        BAR(); mma(b0, 0, 0); BAR();
        // p2 (no same-phase reads)
        stage(t0 + 2, 0, 0);
        BAR(); mma(b1, 0, 1); BAR();
        // p3
        loadA(0, 1);
        stage(t0 + 2, 0, 1);
        BAR(); mma(b1, 1, 1); BAR();
        // p4
        stage(t0 + 2, 0, 2);
        VMCNT(6);                    // tile t0+1 fully landed
        BAR(); mma(b0, 1, 0); loadB(b0, 32768, 0); BAR();
        // p5 (b1 prefetched for p6)
        loadA(32768, 0); loadB(b1, 32768, 1);
        stage(t0 + 2, 0, 3);
        BAR(); mma(b0, 0, 0); BAR();
        // p6 (no same-phase reads)
        stage(t0 + 3, 1, 0);
        BAR(); mma(b1, 0, 1); BAR();
        // p7
        loadA(32768, 1);
        stage(t0 + 3, 1, 1);
        BAR(); mma(b1, 1, 1); BAR();
        // p8
        stage(t0 + 3, 1, 2);
        VMCNT(6);                    // tile t0+2 fully landed
        BAR(); mma(b0, 1, 0); loadB(b0, 0, 0); BAR();
    }
    {   // final iteration (tiles NT-2, NT-1)
        loadA(0, 0); loadB(b1, 0, 1);
        stage(NT - 1, 1, 3);
        BAR(); mma(b0, 0, 0); BAR();
        BAR(); mma(b1, 0, 1); BAR();
        loadA(0, 1);
        BAR(); mma(b1, 1, 1); BAR();
        VMCNT(0);                    // tile NT-1 fully landed
        BAR(); mma(b0, 1, 0); loadB(b0, 32768, 0); BAR();
        loadA(32768, 0); loadB(b1, 32768, 1);
        BAR(); mma(b0, 0, 0); BAR();
        BAR(); mma(b1, 0, 1); BAR();
        loadA(32768, 1);
        BAR(); mma(b1, 1, 1); BAR();
        BAR(); mma(b0, 1, 0);
    }

    // ---- epilogue: LDS bounce (XOR de-conflict) -> coalesced stores ----
    __syncthreads();
    if (EPI == 0) {
        #pragma unroll
        for (int i = 0; i < 8; ++i)
            #pragma unroll
            for (int j = 0; j < 4; ++j)
                #pragma unroll
                for (int reg = 0; reg < 4; ++reg) {
                    int row = wm * 128 + i * 16 + g * 4 + reg;
                    int col = (wn * 64 + j * 16 + lr) ^ ((row & 12) << 2);
                    lds[row * 256 + col] = (f16)acc[i][j][reg];
                }
        __syncthreads();
        #pragma unroll
        for (int k = 0; k < 16; ++k) {
            int e = k * 4096 + tid * 8;          // f16 elem in [256][256]
            int row = e >> 8, col = e & 255;
            *(f16x8*)(Ch + (long)(m0 + row) * N + n0 + col) =
                *(const f16x8*)(lds + row * 256 + (col ^ ((row & 12) << 2)));
        }
    } else {
        float* Ct = (float*)lds;                 // [128][256] f32 per pass
        #pragma unroll
        for (int h = 0; h < 2; ++h) {
            if (h) __syncthreads();
            if (wm == h) {
                #pragma unroll
                for (int i = 0; i < 8; ++i)
                    #pragma unroll
                    for (int j = 0; j < 4; ++j)
                        #pragma unroll
                        for (int reg = 0; reg < 4; ++reg) {
                            int row = i * 16 + g * 4 + reg;
                            int col = (wn * 64 + j * 16 + lr) ^ ((row & 4) << 2);
                            Ct[row * 256 + col] = acc[i][j][reg];
                        }
            }
            float4 ra[8], rb[8];
            #pragma unroll
            for (int k = 0; k < 8; ++k) {
                int e = k * 4096 + tid * 8;
                int row = e >> 8, col = e & 255;
                long gi = (long)(m0 + h * 128 + row) * N + n0 + col;
                ra[k] = *(const float4*)(resid + gi);
                rb[k] = *(const float4*)(resid + gi + 4);
            }
            __syncthreads();
            #pragma unroll
            for (int k = 0; k < 8; ++k) {
                int e = k * 4096 + tid * 8;      // f32 elem in [128][256]
                int row = e >> 8, col = e & 255;
                int pc = col ^ ((row & 4) << 2);
                long gi = (long)(m0 + h * 128 + row) * N + n0 + col;
                float4 c0 = *(const float4*)(Ct + row * 256 + pc);
                float4 c1 = *(const float4*)(Ct + row * 256 + pc + 4);
                c0.x += ra[k].x; c0.y += ra[k].y; c0.z += ra[k].z; c0.w += ra[k].w;
                c1.x += rb[k].x; c1.y += rb[k].y; c1.z += rb[k].z; c1.w += rb[k].w;
                *(float4*)(Cf + gi) = c0;
                *(float4*)(Cf + gi + 4) = c1;
            }
        }
    }
}

// ---- merged q+kv projection: grid 768 (q: 256 blocks, kv: 512 blocks) -----
__global__ __launch_bounds__(512, 2) void gemm_qkv(
        const f16* __restrict__ Aq, const f16* __restrict__ Bq, f16* __restrict__ Cq,
        const f16* __restrict__ Akv, const f16* __restrict__ Bkv, f16* __restrict__ Ckv) {
    int fid = (blockIdx.x & 7) * 96 + (blockIdx.x >> 3);   // XCD swizzle, 768 = 8*96
    const f16 *A, *B; f16* C; int N, lf, sh;
    if (fid < 256) { A = Aq;  B = Bq;  C = Cq;  N = 2048; lf = fid;       sh = 3; }
    else           { A = Akv; B = Bkv; C = Ckv; N = 4096; lf = fid - 256; sh = 4; }
    int by = lf >> sh, bx = lf & ((1 << sh) - 1);
    gemm256_body<0>(A, B, C, nullptr, nullptr, N, 2048, by << 8, bx << 8);
}

// ---- output projection + residual: grid 256 ----
__global__ __launch_bounds__(512, 2) void gemm_out(
        const f16* __restrict__ A, const f16* __restrict__ B,
        float* __restrict__ Cf, const float* __restrict__ resid) {
    int fid = (blockIdx.x & 7) * 32 + (blockIdx.x >> 3);   // 256 = 8*32
    int by = fid >> 3, bx = fid & 7;
    gemm256_body<1>(A, B, nullptr, Cf, resid, 2048, 2048, by << 8, bx << 8);
}

// ---------------- Attention + outw convert: grid 4096 ----------------------
__global__ __launch_bounds__(256, 2) void attn_kern(
        const f16* __restrict__ Q,    // [8192, 2048]
        const f16* __restrict__ KV,   // [8192, 4096]  (k | v)
        const float* __restrict__ mask,      // [64*128]
        const float* __restrict__ bias,      // [32*16]
        float* __restrict__ attn_out,        // (B,L,K,H,R,M) f32
        f16* __restrict__ pv_out,            // [8192, 2048]
        const float* __restrict__ outw, f16* __restrict__ outwh) {
    if (blockIdx.x >= 2048) {   // outw conversion
        long o = (long)(blockIdx.x - 2048) * 2048 + threadIdx.x * 8;
        float4 a = *(const float4*)(outw + o);
        float4 c = *(const float4*)(outw + o + 4);
        f16x8 v = { (f16)a.x,(f16)a.y,(f16)a.z,(f16)a.w,
                    (f16)c.x,(f16)c.y,(f16)c.z,(f16)c.w };
        *(f16x8*)(outwh + o) = v;
        return;
    }
    __shared__ f16 Vt[128 * 128];
    __shared__ f16 P[64 * 136];
    int blk = blockIdx.x;
    int h  = blk & 15;
    int bk = blk >> 4;
    int bl = bk >> 1;
    int tid = threadIdx.x, lane = tid & 63, w = tid >> 6;
    int r0 = w << 4;
    int lr = lane & 15, g = lane >> 4;
    long qbase  = (long)bk * 64 * 2048;
    long kvbase = (long)bl * 128 * 4096;
    f16x8 vreg[8];
    const f16* vsrc = KV + kvbase + 2048 + h * 128;
    #pragma unroll
    for (int rnd = 0; rnd < 8; ++rnd) {
        int idx = tid + rnd * 256;
        vreg[rnd] = *(const f16x8*)(vsrc + (long)(idx >> 4) * 4096 + (idx & 15) * 8);
    }
    f16x8 aq[4];
    const f16* qrow = Q + qbase + (long)(r0 + lr) * 2048 + h * 128 + g * 8;
    #pragma unroll
    for (int t4 = 0; t4 < 4; ++t4) aq[t4] = *(const f16x8*)(qrow + t4 * 32);
    f32x4 s[8] = {};
    const f16* kbase = KV + kvbase + h * 128 + g * 8;
    #pragma unroll
    for (int j = 0; j < 8; ++j) {
        #pragma unroll
        for (int t4 = 0; t4 < 4; ++t4) {
            f16x8 bkf = *(const f16x8*)(kbase + (long)(j * 16 + lr) * 4096 + t4 * 32);
            s[j] = __builtin_amdgcn_mfma_f32_16x16x32_f16(aq[t4], bkf, s[j], 0, 0, 0);
        }
    }
    float madd[8];
    #pragma unroll
    for (int j = 0; j < 8; ++j)
        madd[j] = (1.0f - mask[(long)bl * 128 + j * 16 + lr]) * -10000.0f;
    #pragma unroll
    for (int reg = 0; reg < 4; ++reg) {
        int r = r0 + g * 4 + reg;
        float mx = -3.0e38f;
        #pragma unroll
        for (int j = 0; j < 8; ++j) {
            int m = j * 16 + lr;
            int rel = m - r;
            int bkt = (rel < -15 ? -15 : (rel > 16 ? 16 : rel)) + 15;
            float v = s[j][reg] + bias[bkt * 16 + h] + madd[j];
            s[j][reg] = v;
            mx = fmaxf(mx, v);
        }
        #pragma unroll
        for (int d = 1; d < 16; d <<= 1) mx = fmaxf(mx, __shfl_xor(mx, d, 64));
        float sum = 0.0f;
        #pragma unroll
        for (int j = 0; j < 8; ++j) {
            float e = __expf(s[j][reg] - mx);
            s[j][reg] = e;
            sum += e;
        }
        #pragma unroll
        for (int d = 1; d < 16; d <<= 1) sum += __shfl_xor(sum, d, 64);
        float inv = 1.0f / sum;
        #pragma unroll
        for (int j = 0; j < 8; ++j) s[j][reg] *= inv;
    }
    long abase = (long)blk * 64 * 128;
    #pragma unroll
    for (int reg = 0; reg < 4; ++reg) {
        int r = r0 + g * 4 + reg;
        #pragma unroll
        for (int j = 0; j < 8; ++j) {
            attn_out[abase + (long)r * 128 + j * 16 + lr] = s[j][reg];
            P[r * 136 + j * 16 + lr] = (f16)s[j][reg];
        }
    }
    {
        char* vtb = (char*)Vt;
        #pragma unroll
        for (int rnd = 0; rnd < 8; ++rnd) {
            int idx = tid + rnd * 256;
            int k = idx >> 4, c0 = (idx & 15) * 8;
            #pragma unroll
            for (int i = 0; i < 8; ++i) {
                int c = c0 + i;
                int sx = ((c >> 3) ^ i) & 7;
                *(f16*)(vtb + c * 256 + ((k * 2) ^ (sx << 4))) = vreg[rnd][i];
            }
        }
    }
    __syncthreads();
    f16x8 pa[4];
    #pragma unroll
    for (int t4 = 0; t4 < 4; ++t4)
        pa[t4] = *(const f16x8*)(P + (r0 + lr) * 136 + t4 * 32 + g * 8);
    f32x4 o[8] = {};
    const char* vtb = (const char*)Vt;
    #pragma unroll
    for (int dj = 0; dj < 8; ++dj) {
        int c = dj * 16 + lr;
        int sc = (((c >> 3) ^ (c & 7)) & 7) << 4;
        const char* vrow = vtb + c * 256;
        #pragma unroll
        for (int t4 = 0; t4 < 4; ++t4) {
            f16x8 bv = *(const f16x8*)(vrow + ((t4 * 64 + g * 16) ^ sc));
            o[dj] = __builtin_amdgcn_mfma_f32_16x16x32_f16(pa[t4], bv, o[dj], 0, 0, 0);
        }
    }
    __syncthreads();
    #pragma unroll
    for (int dj = 0; dj < 8; ++dj)
        #pragma unroll
        for (int reg = 0; reg < 4; ++reg) {
            int row = r0 + g * 4 + reg;
            int col = (dj * 16 + lr) ^ ((row & 12) << 2);
            Vt[row * 128 + col] = (f16)o[dj][reg];
        }
    __syncthreads();
    f16* ob = pv_out + qbase + h * 128;
    #pragma unroll
    for (int k = 0; k < 4; ++k) {
        int e = k * 2048 + tid * 8;
        int row = e >> 7, col = e & 127;
        *(f16x8*)(ob + (long)row * 2048 + col) =
            *(const f16x8*)(Vt + row * 128 + (col ^ ((row & 12) << 2)));
    }
}

extern "C" void kernel_launch(void* const* d_in, const int* in_sizes, int n_in,
                              void* d_out, int out_size, void* d_ws, size_t ws_size,
                              hipStream_t stream) {
    const float* x     = (const float*)d_in[0];
    const float* hid   = (const float*)d_in[1];
    const float* mask  = (const float*)d_in[2];
    const float* lnsc  = (const float*)d_in[3];
    const float* q_w   = (const float*)d_in[4];
    const float* kv_w  = (const float*)d_in[5];
    const float* out_w = (const float*)d_in[6];
    const float* bias  = (const float*)d_in[7];
    float* out0 = (float*)d_out;             // (B,L,K,R,Dm) = 16,777,216 f32
    float* attn = out0 + 16777216;           // (B,L,K,H,R,M) = 16,777,216 f32

    f16* kv_h  = (f16*)out0;                 // dead until final GEMM
    f16* xn_h  = (f16*)attn;                 // dead until attn_kern writes attn
    f16* hid_h = (f16*)(attn + 8388608);
    char* ws = (char*)d_ws;
    f16* q_h    = (f16*)(ws);                 // 32 MiB
    f16* ao_h   = (f16*)(ws + 33554432L);     // 32 MiB
    f16* qw_h   = (f16*)(ws + 67108864L);     //  8 MiB
    f16* kvw_h  = (f16*)(ws + 75497472L);     // 16 MiB
    f16* outw_h = (f16*)(ws + 92274688L);     //  8 MiB -> 96 MiB total

    prep_kern<<<22528, 256, 0, stream>>>(q_w, qw_h, kv_w, kvw_h,
                                         hid, hid_h, x, lnsc, xn_h);
    gemm_qkv<<<768, 512, 0, stream>>>(xn_h, qw_h, q_h, hid_h, kvw_h, kv_h);
    attn_kern<<<4096, 256, 0, stream>>>(q_h, kv_h, mask, bias, attn, ao_h,
                                        out_w, outw_h);
    gemm_out<<<256, 512, 0, stream>>>(ao_h, outw_h, out0, x);
}

// Round 16
// 368.088 us; speedup vs baseline: 1.4905x; 1.0073x over previous
//
#include <hip/hip_runtime.h>

typedef _Float16 f16;
typedef _Float16 f16x8 __attribute__((ext_vector_type(8)));
typedef float f32x4 __attribute__((ext_vector_type(4)));

#define LDS_GL16(g, l) __builtin_amdgcn_global_load_lds( \
    (const __attribute__((address_space(1))) void*)(g),  \
    (__attribute__((address_space(3))) void*)(l), 16, 0, 0)
#define VMCNT(N) asm volatile("s_waitcnt vmcnt(" #N ")" ::: "memory")
#define BAR() __builtin_amdgcn_s_barrier()

// ---- fused prep: f32->f16 converts (qw/kvw/hid) + RMSNorm -----------------
// blocks: qw 2048 | kvw 4096 | hid 8192 | rms 8192  (22528)
__global__ __launch_bounds__(256) void prep_kern(
        const float* __restrict__ qw,   f16* __restrict__ qwh,
        const float* __restrict__ kvw,  f16* __restrict__ kvwh,
        const float* __restrict__ hid,  f16* __restrict__ hidh,
        const float* __restrict__ x, const float* __restrict__ lnsc,
        f16* __restrict__ xnh) {
    int b = blockIdx.x;
    if (b >= 14336) {   // RMSNorm row
        long base = (long)(b - 14336) * 2048 + threadIdx.x * 8;
        float4 a = *(const float4*)(x + base);
        float4 v = *(const float4*)(x + base + 4);
        float ss = a.x*a.x + a.y*a.y + a.z*a.z + a.w*a.w
                 + v.x*v.x + v.y*v.y + v.z*v.z + v.w*v.w;
        #pragma unroll
        for (int d = 1; d < 64; d <<= 1) ss += __shfl_xor(ss, d, 64);
        __shared__ float red[4];
        if ((threadIdx.x & 63) == 0) red[threadIdx.x >> 6] = ss;
        __syncthreads();
        ss = red[0] + red[1] + red[2] + red[3];
        float inv = 1.0f / (sqrtf(ss * (1.0f / 2048.0f)) + 1e-8f);
        int c = threadIdx.x * 8;
        float4 s1 = *(const float4*)(lnsc + c);
        float4 s2 = *(const float4*)(lnsc + c + 4);
        f16x8 o = { (f16)(a.x*inv*s1.x),(f16)(a.y*inv*s1.y),(f16)(a.z*inv*s1.z),(f16)(a.w*inv*s1.w),
                    (f16)(v.x*inv*s2.x),(f16)(v.y*inv*s2.y),(f16)(v.z*inv*s2.z),(f16)(v.w*inv*s2.w) };
        *(f16x8*)(xnh + base) = o;
        return;
    }
    const float* in; f16* out; long base;
    if (b < 2048)       { in = qw;   out = qwh;   base = (long)b * 2048; }
    else if (b < 6144)  { in = kvw;  out = kvwh;  base = (long)(b - 2048) * 2048; }
    else                { in = hid;  out = hidh;  base = (long)(b - 6144) * 2048; }
    long o = base + threadIdx.x * 8;
    float4 a = *(const float4*)(in + o);
    float4 c = *(const float4*)(in + o + 4);
    f16x8 v = { (f16)a.x,(f16)a.y,(f16)a.z,(f16)a.w,
                (f16)c.x,(f16)c.y,(f16)c.z,(f16)c.w };
    *(f16x8*)(out + o) = v;
}

// ---------------- GEMM 256x256 body, BK=64, 8 waves, 8-phase pipelined -----
// C[M,N] = A[M,K] * B[N,K]^T.  EPI=0: f16 out. EPI=1: f32 out + resid.
// R9-proven schedule: vmcnt(6) at p4/p8 only; b0 preloaded post-mma there.
template<int EPI>
__device__ __forceinline__ void gemm256_body(
        const f16* __restrict__ A, const f16* __restrict__ B,
        f16* __restrict__ Ch, float* __restrict__ Cf,
        const float* __restrict__ resid, int N, int Kd, int m0, int n0) {
    alignas(16) __shared__ f16 lds[65536];
    int tid = threadIdx.x, lane = tid & 63;
    int wid = tid >> 6, wm = wid >> 2, wn = wid & 3;
    int lr = lane & 15, g = lane >> 4;
    int iL = tid >> 3, cb = tid & 7;

    long goff[8]; int doff[8];
    #pragma unroll
    for (int rd = 0; rd < 2; ++rd) {
        int rA0 = iL + rd * 128;
        goff[0 + rd] = (long)(m0 + rA0) * Kd + ((cb ^ (rA0 & 7)) << 3);
        doff[0 + rd] = rA0 * 64 + cb * 8;
        int rB0 = (iL & 31) + ((iL >> 5) + rd * 2) * 64;
        goff[2 + rd] = (long)(n0 + rB0) * Kd + ((cb ^ (rB0 & 7)) << 3);
        doff[2 + rd] = 32768 + rB0 * 64 + cb * 8;
        int rB1 = rB0 + 32;
        goff[4 + rd] = (long)(n0 + rB1) * Kd + ((cb ^ (rB1 & 7)) << 3);
        doff[4 + rd] = 32768 + rB1 * 64 + cb * 8;
        int rA1 = rA0 + 64;
        goff[6 + rd] = (long)(m0 + rA1) * Kd + ((cb ^ (rA1 & 7)) << 3);
        doff[6 + rd] = rA1 * 64 + cb * 8;
    }
    auto stage = [&](int kt, int p, int r) {
        const f16* src = (r == 0 || r == 3) ? A : B;
        #pragma unroll
        for (int rd = 0; rd < 2; ++rd)
            LDS_GL16(src + goff[r * 2 + rd] + kt * 64,
                     lds + p * 16384 + doff[r * 2 + rd]);
    };

    const char* ldsc = (const char*)lds;
    int swz = lr & 7;
    const char* baseA[2], *baseB[2];
    baseA[0] = ldsc + (wm * 128 + lr) * 128 + ((g ^ swz) << 4);
    baseA[1] = ldsc + (wm * 128 + lr) * 128 + (((4 + g) ^ swz) << 4);
    baseB[0] = ldsc + 65536 + (wn * 64 + lr) * 128 + ((g ^ swz) << 4);
    baseB[1] = ldsc + 65536 + (wn * 64 + lr) * 128 + (((4 + g) ^ swz) << 4);

    f32x4 acc[8][4] = {};
    f16x8 a[4][2], b0[2][2], b1[2][2];

    auto loadA = [&](int bufB, int qm) {
        #pragma unroll
        for (int mf = 0; mf < 4; ++mf)
            #pragma unroll
            for (int kk = 0; kk < 2; ++kk)
                a[mf][kk] = *(const f16x8*)(baseA[kk] + bufB + qm * 8192 + mf * 2048);
    };
    auto loadB = [&](f16x8 (&d)[2][2], int bufB, int qn) {
        #pragma unroll
        for (int nf = 0; nf < 2; ++nf)
            #pragma unroll
            for (int kk = 0; kk < 2; ++kk)
                d[nf][kk] = *(const f16x8*)(baseB[kk] + bufB + qn * 4096 + nf * 2048);
    };
    auto mma = [&](f16x8 (&bb)[2][2], int qm, int qn) {
        __builtin_amdgcn_s_setprio(1);
        #pragma unroll
        for (int kk = 0; kk < 2; ++kk)
            #pragma unroll
            for (int mf = 0; mf < 4; ++mf)
                #pragma unroll
                for (int nf = 0; nf < 2; ++nf)
                    acc[qm * 4 + mf][qn * 2 + nf] = __builtin_amdgcn_mfma_f32_16x16x32_f16(
                        a[mf][kk], bb[nf][kk], acc[qm * 4 + mf][qn * 2 + nf], 0, 0, 0);
        __builtin_amdgcn_s_setprio(0);
    };

    int NT = Kd >> 6, NI = NT >> 1;

    stage(0, 0, 0); stage(0, 0, 1); stage(0, 0, 2); stage(0, 0, 3);
    stage(1, 1, 0); stage(1, 1, 1); stage(1, 1, 2);
    VMCNT(6); BAR();                 // tile0 landed; 6 in flight
    loadB(b0, 0, 0);                 // preload b0 for first p1

    for (int it = 0; it < NI - 1; ++it) {
        int t0 = it * 2;
        // p1
        loadA(0, 0);
        stage(t0 + 1, 1, 3);
        BAR(); mma(b0, 0, 0); BAR();
        // p2
        loadB(b1, 0, 1);
        stage(t0 + 2, 0, 0);
        BAR(); mma(b1, 0, 1); BAR();
        // p3
        loadA(0, 1);
        stage(t0 + 2, 0, 1);
        BAR(); mma(b1, 1, 1); BAR();
        // p4
        stage(t0 + 2, 0, 2);
        VMCNT(6);                    // tile t0+1 fully landed
        BAR(); mma(b0, 1, 0); loadB(b0, 32768, 0); BAR();
        // p5
        loadA(32768, 0);
        stage(t0 + 2, 0, 3);
        BAR(); mma(b0, 0, 0); BAR();
        // p6
        loadB(b1, 32768, 1);
        stage(t0 + 3, 1, 0);
        BAR(); mma(b1, 0, 1); BAR();
        // p7
        loadA(32768, 1);
        stage(t0 + 3, 1, 1);
        BAR(); mma(b1, 1, 1); BAR();
        // p8
        stage(t0 + 3, 1, 2);
        VMCNT(6);                    // tile t0+2 fully landed
        BAR(); mma(b0, 1, 0); loadB(b0, 0, 0); BAR();
    }
    {   // final iteration (tiles NT-2, NT-1)
        loadA(0, 0);
        stage(NT - 1, 1, 3);
        BAR(); mma(b0, 0, 0); BAR();
        loadB(b1, 0, 1);
        BAR(); mma(b1, 0, 1); BAR();
        loadA(0, 1);
        BAR(); mma(b1, 1, 1); BAR();
        VMCNT(0);                    // tile NT-1 fully landed
        BAR(); mma(b0, 1, 0); loadB(b0, 32768, 0); BAR();
        loadA(32768, 0);
        BAR(); mma(b0, 0, 0); BAR();
        loadB(b1, 32768, 1);
        BAR(); mma(b1, 0, 1); BAR();
        loadA(32768, 1);
        BAR(); mma(b1, 1, 1); BAR();
        BAR(); mma(b0, 1, 0);
    }

    // ---- epilogue: LDS bounce (XOR de-conflict) -> coalesced stores ----
    __syncthreads();
    if (EPI == 0) {
        #pragma unroll
        for (int i = 0; i < 8; ++i)
            #pragma unroll
            for (int j = 0; j < 4; ++j)
                #pragma unroll
                for (int reg = 0; reg < 4; ++reg) {
                    int row = wm * 128 + i * 16 + g * 4 + reg;
                    int col = (wn * 64 + j * 16 + lr) ^ ((row & 12) << 2);
                    lds[row * 256 + col] = (f16)acc[i][j][reg];
                }
        __syncthreads();
        #pragma unroll
        for (int k = 0; k < 16; ++k) {
            int e = k * 4096 + tid * 8;          // f16 elem in [256][256]
            int row = e >> 8, col = e & 255;
            *(f16x8*)(Ch + (long)(m0 + row) * N + n0 + col) =
                *(const f16x8*)(lds + row * 256 + (col ^ ((row & 12) << 2)));
        }
    } else {
        float* Ct = (float*)lds;                 // [128][256] f32 per pass
        #pragma unroll
        for (int h = 0; h < 2; ++h) {
            if (h) __syncthreads();
            if (wm == h) {
                #pragma unroll
                for (int i = 0; i < 8; ++i)
                    #pragma unroll
                    for (int j = 0; j < 4; ++j)
                        #pragma unroll
                        for (int reg = 0; reg < 4; ++reg) {
                            int row = i * 16 + g * 4 + reg;
                            int col = (wn * 64 + j * 16 + lr) ^ ((row & 4) << 2);
                            Ct[row * 256 + col] = acc[i][j][reg];
                        }
            }
            float4 ra[8], rb[8];
            #pragma unroll
            for (int k = 0; k < 8; ++k) {
                int e = k * 4096 + tid * 8;
                int row = e >> 8, col = e & 255;
                long gi = (long)(m0 + h * 128 + row) * N + n0 + col;
                ra[k] = *(const float4*)(resid + gi);
                rb[k] = *(const float4*)(resid + gi + 4);
            }
            __syncthreads();
            #pragma unroll
            for (int k = 0; k < 8; ++k) {
                int e = k * 4096 + tid * 8;      // f32 elem in [128][256]
                int row = e >> 8, col = e & 255;
                int pc = col ^ ((row & 4) << 2);
                long gi = (long)(m0 + h * 128 + row) * N + n0 + col;
                float4 c0 = *(const float4*)(Ct + row * 256 + pc);
                float4 c1 = *(const float4*)(Ct + row * 256 + pc + 4);
                c0.x += ra[k].x; c0.y += ra[k].y; c0.z += ra[k].z; c0.w += ra[k].w;
                c1.x += rb[k].x; c1.y += rb[k].y; c1.z += rb[k].z; c1.w += rb[k].w;
                *(float4*)(Cf + gi) = c0;
                *(float4*)(Cf + gi + 4) = c1;
            }
        }
    }
}

// ---- merged q+kv projection: grid 768 (q: 256 blocks, kv: 512 blocks) -----
__global__ __launch_bounds__(512, 2) void gemm_qkv(
        const f16* __restrict__ Aq, const f16* __restrict__ Bq, f16* __restrict__ Cq,
        const f16* __restrict__ Akv, const f16* __restrict__ Bkv, f16* __restrict__ Ckv) {
    int fid = (blockIdx.x & 7) * 96 + (blockIdx.x >> 3);   // XCD swizzle, 768 = 8*96
    const f16 *A, *B; f16* C; int N, lf, sh;
    if (fid < 256) { A = Aq;  B = Bq;  C = Cq;  N = 2048; lf = fid;       sh = 3; }
    else           { A = Akv; B = Bkv; C = Ckv; N = 4096; lf = fid - 256; sh = 4; }
    int by = lf >> sh, bx = lf & ((1 << sh) - 1);
    gemm256_body<0>(A, B, C, nullptr, nullptr, N, 2048, by << 8, bx << 8);
}

// ---- output projection + residual: grid 256 ----
__global__ __launch_bounds__(512, 2) void gemm_out(
        const f16* __restrict__ A, const f16* __restrict__ B,
        float* __restrict__ Cf, const float* __restrict__ resid) {
    int fid = (blockIdx.x & 7) * 32 + (blockIdx.x >> 3);   // 256 = 8*32
    int by = fid >> 3, bx = fid & 7;
    gemm256_body<1>(A, B, nullptr, Cf, resid, 2048, 2048, by << 8, bx << 8);
}

// ---------------- Attention + outw convert: grid 4096 ----------------------
// blocks 0..2047: one (b,l,k,h) attn tile.  blocks 2048..4095: outw f32->f16
// (needed only by the LATER gemm_out launch; conversion hides under attn).
__global__ __launch_bounds__(256, 2) void attn_kern(
        const f16* __restrict__ Q,    // [8192, 2048]
        const f16* __restrict__ KV,   // [8192, 4096]  (k | v)
        const float* __restrict__ mask,      // [64*128]
        const float* __restrict__ bias,      // [32*16]
        float* __restrict__ attn_out,        // (B,L,K,H,R,M) f32
        f16* __restrict__ pv_out,            // [8192, 2048]
        const float* __restrict__ outw, f16* __restrict__ outwh) {
    if (blockIdx.x >= 2048) {   // outw conversion
        long o = (long)(blockIdx.x - 2048) * 2048 + threadIdx.x * 8;
        float4 a = *(const float4*)(outw + o);
        float4 c = *(const float4*)(outw + o + 4);
        f16x8 v = { (f16)a.x,(f16)a.y,(f16)a.z,(f16)a.w,
                    (f16)c.x,(f16)c.y,(f16)c.z,(f16)c.w };
        *(f16x8*)(outwh + o) = v;
        return;
    }
    __shared__ f16 Vt[128 * 128];
    __shared__ f16 P[64 * 136];
    int blk = blockIdx.x;
    int h  = blk & 15;
    int bk = blk >> 4;
    int bl = bk >> 1;
    int tid = threadIdx.x, lane = tid & 63, w = tid >> 6;
    int r0 = w << 4;
    int lr = lane & 15, g = lane >> 4;
    long qbase  = (long)bk * 64 * 2048;
    long kvbase = (long)bl * 128 * 4096;
    f16x8 vreg[8];
    const f16* vsrc = KV + kvbase + 2048 + h * 128;
    #pragma unroll
    for (int rnd = 0; rnd < 8; ++rnd) {
        int idx = tid + rnd * 256;
        vreg[rnd] = *(const f16x8*)(vsrc + (long)(idx >> 4) * 4096 + (idx & 15) * 8);
    }
    f16x8 aq[4];
    const f16* qrow = Q + qbase + (long)(r0 + lr) * 2048 + h * 128 + g * 8;
    #pragma unroll
    for (int t4 = 0; t4 < 4; ++t4) aq[t4] = *(const f16x8*)(qrow + t4 * 32);
    f32x4 s[8] = {};
    const f16* kbase = KV + kvbase + h * 128 + g * 8;
    #pragma unroll
    for (int j = 0; j < 8; ++j) {
        #pragma unroll
        for (int t4 = 0; t4 < 4; ++t4) {
            f16x8 bkf = *(const f16x8*)(kbase + (long)(j * 16 + lr) * 4096 + t4 * 32);
            s[j] = __builtin_amdgcn_mfma_f32_16x16x32_f16(aq[t4], bkf, s[j], 0, 0, 0);
        }
    }
    float madd[8];
    #pragma unroll
    for (int j = 0; j < 8; ++j)
        madd[j] = (1.0f - mask[(long)bl * 128 + j * 16 + lr]) * -10000.0f;
    #pragma unroll
    for (int reg = 0; reg < 4; ++reg) {
        int r = r0 + g * 4 + reg;
        float mx = -3.0e38f;
        #pragma unroll
        for (int j = 0; j < 8; ++j) {
            int m = j * 16 + lr;
            int rel = m - r;
            int bkt = (rel < -15 ? -15 : (rel > 16 ? 16 : rel)) + 15;
            float v = s[j][reg] + bias[bkt * 16 + h] + madd[j];
            s[j][reg] = v;
            mx = fmaxf(mx, v);
        }
        #pragma unroll
        for (int d = 1; d < 16; d <<= 1) mx = fmaxf(mx, __shfl_xor(mx, d, 64));
        float sum = 0.0f;
        #pragma unroll
        for (int j = 0; j < 8; ++j) {
            float e = __expf(s[j][reg] - mx);
            s[j][reg] = e;
            sum += e;
        }
        #pragma unroll
        for (int d = 1; d < 16; d <<= 1) sum += __shfl_xor(sum, d, 64);
        float inv = 1.0f / sum;
        #pragma unroll
        for (int j = 0; j < 8; ++j) s[j][reg] *= inv;
    }
    long abase = (long)blk * 64 * 128;
    #pragma unroll
    for (int reg = 0; reg < 4; ++reg) {
        int r = r0 + g * 4 + reg;
        #pragma unroll
        for (int j = 0; j < 8; ++j) {
            attn_out[abase + (long)r * 128 + j * 16 + lr] = s[j][reg];
            P[r * 136 + j * 16 + lr] = (f16)s[j][reg];
        }
    }
    {
        char* vtb = (char*)Vt;
        #pragma unroll
        for (int rnd = 0; rnd < 8; ++rnd) {
            int idx = tid + rnd * 256;
            int k = idx >> 4, c0 = (idx & 15) * 8;
            #pragma unroll
            for (int i = 0; i < 8; ++i) {
                int c = c0 + i;
                int sx = ((c >> 3) ^ i) & 7;
                *(f16*)(vtb + c * 256 + ((k * 2) ^ (sx << 4))) = vreg[rnd][i];
            }
        }
    }
    __syncthreads();
    f16x8 pa[4];
    #pragma unroll
    for (int t4 = 0; t4 < 4; ++t4)
        pa[t4] = *(const f16x8*)(P + (r0 + lr) * 136 + t4 * 32 + g * 8);
    f32x4 o[8] = {};
    const char* vtb = (const char*)Vt;
    #pragma unroll
    for (int dj = 0; dj < 8; ++dj) {
        int c = dj * 16 + lr;
        int sc = (((c >> 3) ^ (c & 7)) & 7) << 4;
        const char* vrow = vtb + c * 256;
        #pragma unroll
        for (int t4 = 0; t4 < 4; ++t4) {
            f16x8 bv = *(const f16x8*)(vrow + ((t4 * 64 + g * 16) ^ sc));
            o[dj] = __builtin_amdgcn_mfma_f32_16x16x32_f16(pa[t4], bv, o[dj], 0, 0, 0);
        }
    }
    __syncthreads();
    #pragma unroll
    for (int dj = 0; dj < 8; ++dj)
        #pragma unroll
        for (int reg = 0; reg < 4; ++reg) {
            int row = r0 + g * 4 + reg;
            int col = (dj * 16 + lr) ^ ((row & 12) << 2);
            Vt[row * 128 + col] = (f16)o[dj][reg];
        }
    __syncthreads();
    f16* ob = pv_out + qbase + h * 128;
    #pragma unroll
    for (int k = 0; k < 4; ++k) {
        int e = k * 2048 + tid * 8;
        int row = e >> 7, col = e & 127;
        *(f16x8*)(ob + (long)row * 2048 + col) =
            *(const f16x8*)(Vt + row * 128 + (col ^ ((row & 12) << 2)));
    }
}

extern "C" void kernel_launch(void* const* d_in, const int* in_sizes, int n_in,
                              void* d_out, int out_size, void* d_ws, size_t ws_size,
                              hipStream_t stream) {
    const float* x     = (const float*)d_in[0];
    const float* hid   = (const float*)d_in[1];
    const float* mask  = (const float*)d_in[2];
    const float* lnsc  = (const float*)d_in[3];
    const float* q_w   = (const float*)d_in[4];
    const float* kv_w  = (const float*)d_in[5];
    const float* out_w = (const float*)d_in[6];
    const float* bias  = (const float*)d_in[7];
    float* out0 = (float*)d_out;             // (B,L,K,R,Dm) = 16,777,216 f32
    float* attn = out0 + 16777216;           // (B,L,K,H,R,M) = 16,777,216 f32

    f16* kv_h  = (f16*)out0;                 // dead until final GEMM
    f16* xn_h  = (f16*)attn;                 // dead until attn_kern writes attn
    f16* hid_h = (f16*)(attn + 8388608);
    char* ws = (char*)d_ws;
    f16* q_h    = (f16*)(ws);                 // 32 MiB
    f16* ao_h   = (f16*)(ws + 33554432L);     // 32 MiB
    f16* qw_h   = (f16*)(ws + 67108864L);     //  8 MiB
    f16* kvw_h  = (f16*)(ws + 75497472L);     // 16 MiB
    f16* outw_h = (f16*)(ws + 92274688L);     //  8 MiB -> 96 MiB total

    prep_kern<<<22528, 256, 0, stream>>>(q_w, qw_h, kv_w, kvw_h,
                                         hid, hid_h, x, lnsc, xn_h);
    gemm_qkv<<<768, 512, 0, stream>>>(xn_h, qw_h, q_h, hid_h, kvw_h, kv_h);
    attn_kern<<<4096, 256, 0, stream>>>(q_h, kv_h, mask, bias, attn, ao_h,
                                        out_w, outw_h);
    gemm_out<<<256, 512, 0, stream>>>(ao_h, outw_h, out0, x);
}